// Round 3
// baseline (182.140 us; speedup 1.0000x reference)
//
#include <hip/hip_runtime.h>

// TeamMovementModel R14: three VALU cuts on the R13 structure (106.6us).
// R13 counters: active-CU VALUBusy ~46%, MfmaUtil ~31%, ~23% both-idle.
// Per-wave VALU/substep ~230cyc: trans 16x8=128, acc-init movs 32, nonlin ~44.
// Changes vs R13:
//  1. Bias-as-C: aug MFMA runs FIRST with persistent bias4[mi] as C-input ->
//     16 acc-init movs gone; chain opener independent of h ds_reads.
//  2. One-rcp c-update: c = (c*dA + K2*(G-1)*e) * rcp(dA*e), dA=(1+A)(G+1),
//     e=1+F. Exact rewrite of f*c+i*g; 8 -> 7 trans per output (14/lane).
//  3. Issue order: x_tab read first, then bfr ds_reads, then aug MFMAs ->
//     x_tab's lgkm wait doesn't drain bfr; aug MFMAs hide h-read latency.
// Predicted: kernel ~95-99us, VALUBusy ~29-30, MfmaUtil ~24, VGPR ~128.

#define HDIM 128
#define TSTEPS 128
#define NPLAYER 1408
#define NSEQ 1472
#define NB 8
#define NBLK (NSEQ / NB)        // 184
#define NPBLK (NPLAYER / NB)    // 176
#define KT 5                    // k-tiles of 32 (K_aug = 160; kt4 = x aug)
#define BSTR 168                // fp16 per B row (336 B stride, proven layout)
#define HSTR 132                // floats per hbuf row (16B-aligned, pad 4)

typedef _Float16 f16x8 __attribute__((ext_vector_type(8)));
typedef _Float16 f16x2 __attribute__((ext_vector_type(2)));
typedef float    f32x4 __attribute__((ext_vector_type(4)));

#define LOG2E 1.4426950408889634f
#define K2    2.8853900817779268f   // 2*log2(e)

__device__ __forceinline__ float rcp_fast(float x)  { return __builtin_amdgcn_rcpf(x); }
__device__ __forceinline__ float exp2_fast(float x) { return __builtin_amdgcn_exp2f(x); }

__global__ void __launch_bounds__(512)
__attribute__((amdgpu_waves_per_eu(2, 2)))
lstm_fc_kernel(const float* __restrict__ x_players, const float* __restrict__ x_ball,
               const float* __restrict__ p_w_ih, const float* __restrict__ p_w_hh,
               const float* __restrict__ p_b_ih, const float* __restrict__ p_b_hh,
               const float* __restrict__ b_w_ih, const float* __restrict__ b_w_hh,
               const float* __restrict__ b_b_ih, const float* __restrict__ b_b_hh,
               const float* __restrict__ fc_w, const float* __restrict__ fc_b,
               float* __restrict__ out)
{
    const int tid  = threadIdx.x;
    const int blk  = blockIdx.x;          // 0..183; 176..183 ball
    const int w    = tid >> 6;            // wave -> h-rows [16w, 16w+16)
    const int lane = tid & 63;
    const int nn   = lane & 15;           // MFMA n (col)
    const int q    = lane >> 4;           // MFMA quad

    const bool ball = (blk >= NPBLK);
    const float* w_ih = ball ? b_w_ih : p_w_ih;
    const float* w_hh = ball ? b_w_hh : p_w_hh;
    const float* bih  = ball ? b_b_ih : p_b_ih;
    const float* bhh  = ball ? b_b_hh : p_b_hh;
    const float* xg   = ball ? (x_ball    + (size_t)(blk - NPBLK) * NB * TSTEPS * 2)
                             : (x_players + (size_t)blk * NB * TSTEPS * 2);

    __shared__ __align__(16) _Float16 b_sh[2][NB * BSTR];
    __shared__ __align__(4)  f16x2 x_tab[TSTEPS * NB];   // [t][seq], fp16 pairs
    __shared__ __align__(16) float hbuf[NB * HSTR];      // final h, fp32
    __shared__ float vout[NB * 40];                      // ball-path per-batch fc part

    // zero h double-buffers (buf0 = h(-1) = 0; buf1 fully overwritten each step)
    for (int i = tid; i < 2 * NB * BSTR / 2; i += 512)
        ((int*)b_sh)[i] = 0;
    // static fp16 x table (coalesced: t fastest)
    for (int i = tid; i < TSTEPS * NB; i += 512) {
        const int sq = i >> 7, t = i & 127;
        const float2 xv2 = ((const float2*)xg)[sq * TSTEPS + t];
        x_tab[t * NB + sq] = (f16x2){(_Float16)xv2.x, (_Float16)xv2.y};
    }

    // ---- A fragments (pre-scaled): gate mi, row r = mi*128 + 16w + nn.
    // a[j] = A[m=lane&15][k = 32kt + 8q + j]; kt=4 aug: k=128:wi0 129:wi1
    const int rowoff = (nn < 8) ? 0 : 2;        // which acc regs this lane keeps
    f16x8 afr[4][KT];
    f32x4 bias4[4];                             // persistent aug-MFMA C input
    #pragma unroll
    for (int mi = 0; mi < 4; ++mi) {
        const float sc = (mi == 2) ? K2 : LOG2E;   // g gate gets 2*log2e
        const int r = mi * HDIM + w * 16 + nn;
        const float* wr = w_hh + (size_t)r * HDIM;
        #pragma unroll
        for (int kt = 0; kt < 4; ++kt) {
            const float* p = wr + kt * 32 + q * 8;
            f16x8 a8;
            #pragma unroll
            for (int j = 0; j < 8; ++j) a8[j] = (_Float16)(sc * p[j]);
            afr[mi][kt] = a8;
        }
        f16x8 a8 = {};
        if (q == 0) {
            a8[0] = (_Float16)(sc * w_ih[2 * r]);
            a8[1] = (_Float16)(sc * w_ih[2 * r + 1]);
        }
        afr[mi][4] = a8;
        // bias for this lane's kept C/D rows (4q+rowoff, +1), pre-scaled.
        // C layout: reg j = row 4q+j; only regs {rowoff, rowoff+1} are kept,
        // so {b0,b1,b0,b1} is correct for both nn<8 (regs 0,1) and nn>=8 (2,3).
        const int rb = mi * HDIM + w * 16 + 4 * q + rowoff;
        const float b0 = sc * (bih[rb] + bhh[rb]);
        const float b1 = sc * (bih[rb + 1] + bhh[rb + 1]);
        bias4[mi] = (f32x4){b0, b1, b0, b1};
    }

    const int colh = nn & 7;                    // owned seq col (dup across nn^8)
    const int hrow = w * 16 + 4 * q + rowoff;   // first of 2 owned h-rows
    float c0 = 0.f, c1 = 0.f;                   // c kept in 2*log2e scale
    float h0 = 0.f, h1 = 0.f;

    __syncthreads();

    f16x8 bx = {};   // aug B frag: words 2..7 stay zero forever

    auto substep = [&](int s, const _Float16* bc, _Float16* bn, bool last) {
        // x first: its lgkm wait must not drain the bfr reads issued after it
        const f16x2 xv = x_tab[s * NB + colh];
        f16x8 bfr[4];
        const _Float16* bp = bc + colh * BSTR + q * 8;
        #pragma unroll
        for (int kt = 0; kt < 4; ++kt)
            bfr[kt] = *(const f16x8*)(bp + kt * 32);
        bx[0] = xv[0]; bx[1] = xv[1];

        // aug MFMA first: C = persistent bias, independent of h ds_reads
        f32x4 acc[4];
        #pragma unroll
        for (int mi = 0; mi < 4; ++mi)
            acc[mi] = __builtin_amdgcn_mfma_f32_16x16x32_f16(afr[mi][4], bx, bias4[mi], 0, 0, 0);
        #pragma unroll
        for (int kt = 0; kt < 4; ++kt)
            #pragma unroll
            for (int mi = 0; mi < 4; ++mi)
                acc[mi] = __builtin_amdgcn_mfma_f32_16x16x32_f16(afr[mi][kt], bfr[kt], acc[mi], 0, 0, 0);

        // B cols duplicated -> lane nn>=8's own regs {2,3} are rows 4q+2,4q+3
        float u0[4], u1[4];
        #pragma unroll
        for (int mi = 0; mi < 4; ++mi) {
            u0[mi] = (nn < 8) ? acc[mi][0] : acc[mi][2];
            u1[mi] = (nn < 8) ? acc[mi][1] : acc[mi][3];
        }

        // u pre-scaled: [0]=i',[1]=f',[3]=o' (log2e); [2]=g' (2*log2e)
        const float A0 = exp2_fast(-u0[0]), A1 = exp2_fast(-u1[0]);
        const float F0 = exp2_fast(-u0[1]), F1 = exp2_fast(-u1[1]);
        const float G0 = exp2_fast( u0[2]), G1 = exp2_fast( u1[2]);
        const float O0 = exp2_fast(-u0[3]), O1 = exp2_fast(-u1[3]);
        // c' = f*c' + K2*i*g  ==  (c'*dA + K2*(G-1)*e) / (dA*e),
        // dA = (1+A)(G+1), e = 1+F   (one rcp instead of two)
        const float dA0 = (1.0f + A0) * (G0 + 1.0f);
        const float dA1 = (1.0f + A1) * (G1 + 1.0f);
        const float t0  = __builtin_fmaf(G0, K2, -K2);
        const float t1  = __builtin_fmaf(G1, K2, -K2);
        const float e0  = 1.0f + F0;
        const float e1  = 1.0f + F1;
        const float rd0 = rcp_fast(dA0 * e0);
        const float rd1 = rcp_fast(dA1 * e1);
        c0 = __builtin_fmaf(c0, dA0, t0 * e0) * rd0;
        c1 = __builtin_fmaf(c1, dA1, t1 * e1) * rd1;
        const float C0 = exp2_fast(c0), C1 = exp2_fast(c1);
        // h = o*tanh(c) = (C-1) * rcp((C+1)(1+O))
        const float rr0 = rcp_fast((C0 + 1.0f) * (1.0f + O0));
        const float rr1 = rcp_fast((C1 + 1.0f) * (1.0f + O1));
        h0 = (C0 - 1.0f) * rr0;
        h1 = (C1 - 1.0f) * rr1;

        if (!last) {
            *(f16x2*)&bn[colh * BSTR + hrow] = (f16x2){(_Float16)h0, (_Float16)h1};
            __syncthreads();
        }
    };

    _Float16* b0 = &b_sh[0][0];
    _Float16* b1 = &b_sh[1][0];
    #pragma unroll 1
    for (int it = 0; it < TSTEPS / 2 - 1; ++it) {   // steps 0..125
        substep(2 * it,     b0, b1, false);
        substep(2 * it + 1, b1, b0, false);
        // loop-carried reg pins: block rematerialization (R1..R5 failure mode)
        asm volatile("" : "+a"(afr[0][0]), "+a"(afr[0][1]), "+a"(afr[0][2]), "+a"(afr[0][3]), "+a"(afr[0][4]));
        asm volatile("" : "+a"(afr[1][0]), "+a"(afr[1][1]), "+a"(afr[1][2]), "+a"(afr[1][3]), "+a"(afr[1][4]));
        asm volatile("" : "+a"(afr[2][0]), "+a"(afr[2][1]), "+a"(afr[2][2]), "+a"(afr[2][3]), "+a"(afr[2][4]));
        asm volatile("" : "+a"(afr[3][0]), "+a"(afr[3][1]), "+a"(afr[3][2]), "+a"(afr[3][3]), "+a"(afr[3][4]));
        asm volatile("" : "+v"(bias4[0]), "+v"(bias4[1]), "+v"(bias4[2]), "+v"(bias4[3]));
    }
    substep(126, b0, b1, false);
    substep(127, b1, b0, true);    // peeled: no h-write, no barrier

    // ---- final h -> LDS (fp32), then fused FC epilogue ----
    hbuf[colh * HSTR + hrow]     = h0;
    hbuf[colh * HSTR + hrow + 1] = h1;
    __syncthreads();

    if (!ball) {
        // player part: out[gp*40+row] += fc_b[row] + fc_w[row, 0:128] . h(gp)
        for (int o = tid; o < NB * 40; o += 512) {
            const int j = o / 40, row = o - j * 40;
            const float* wr = fc_w + (size_t)row * 2 * HDIM;        // cols 0..127
            const float* hp = &hbuf[j * HSTR];
            float a0 = fc_b[row], a1 = 0.f, a2 = 0.f, a3 = 0.f;
            #pragma unroll
            for (int k = 0; k < HDIM; k += 4) {
                float4 wv = *(const float4*)(wr + k);
                float4 hv = *(const float4*)(hp + k);
                a0 = __builtin_fmaf(wv.x, hv.x, a0);
                a1 = __builtin_fmaf(wv.y, hv.y, a1);
                a2 = __builtin_fmaf(wv.z, hv.z, a2);
                a3 = __builtin_fmaf(wv.w, hv.w, a3);
            }
            atomicAdd(&out[(size_t)(NB * blk + j) * 40 + row], (a0 + a1) + (a2 + a3));
        }
    } else {
        // ball part: v[c][row] = fc_w[row, 128:256] . ball_h(batch), then
        // broadcast-add to the batch's 22 players.
        for (int o = tid; o < NB * 40; o += 512) {
            const int c = o / 40, row = o - c * 40;
            const float* wr = fc_w + (size_t)row * 2 * HDIM + HDIM;  // cols 128..255
            const float* hp = &hbuf[c * HSTR];
            float a0 = 0.f, a1 = 0.f, a2 = 0.f, a3 = 0.f;
            #pragma unroll
            for (int k = 0; k < HDIM; k += 4) {
                float4 wv = *(const float4*)(wr + k);
                float4 hv = *(const float4*)(hp + k);
                a0 = __builtin_fmaf(wv.x, hv.x, a0);
                a1 = __builtin_fmaf(wv.y, hv.y, a1);
                a2 = __builtin_fmaf(wv.z, hv.z, a2);
                a3 = __builtin_fmaf(wv.w, hv.w, a3);
            }
            vout[c * 40 + row] = (a0 + a1) + (a2 + a3);
        }
        __syncthreads();
        const int base_batch = (blk - NPBLK) * NB;
        for (int o = tid; o < NB * 22 * 40; o += 512) {
            const int c = o / 880, rem = o - c * 880;
            const int p = rem / 40, row = rem - p * 40;
            atomicAdd(&out[(size_t)((base_batch + c) * 22 + p) * 40 + row],
                      vout[c * 40 + row]);
        }
    }
}

extern "C" void kernel_launch(void* const* d_in, const int* in_sizes, int n_in,
                              void* d_out, int out_size, void* d_ws, size_t ws_size,
                              hipStream_t stream) {
    const float* x_players = (const float*)d_in[0];
    const float* x_ball    = (const float*)d_in[1];
    const float* p_w_ih    = (const float*)d_in[2];
    const float* p_w_hh    = (const float*)d_in[3];
    const float* p_b_ih    = (const float*)d_in[4];
    const float* p_b_hh    = (const float*)d_in[5];
    const float* b_w_ih    = (const float*)d_in[6];
    const float* b_w_hh    = (const float*)d_in[7];
    const float* b_b_ih    = (const float*)d_in[8];
    const float* b_b_hh    = (const float*)d_in[9];
    const float* fc_w      = (const float*)d_in[10];
    const float* fc_b      = (const float*)d_in[11];

    // zero the output: both block types accumulate into it atomically
    hipMemsetAsync(d_out, 0, (size_t)out_size * sizeof(float), stream);

    lstm_fc_kernel<<<dim3(NBLK), dim3(512), 0, stream>>>(
        x_players, x_ball, p_w_ih, p_w_hh, p_b_ih, p_b_hh,
        b_w_ih, b_w_hh, b_b_ih, b_b_hh, fc_w, fc_b, (float*)d_out);
}

// Round 4
// 174.378 us; speedup vs baseline: 1.0445x; 1.0445x over previous
//
#include <hip/hip_runtime.h>

// TeamMovementModel R15: R13 (measured 106.6us) + the two sound R14 cuts with
// the regression mechanism fixed.
// R14 post-mortem: +9pts VALUBusy (+~30 insts/wave/substep) with VGPR flat ->
// "+v"-pinned bias4 forced VGPR<->AGPR shuttling around the aug MFMA's C input.
// R15: bias4 pinned "+a" (AGPR) -> aug MFMA A(a),B(v),C(a)->D(a), no copies.
//  1. Bias-as-C: aug MFMA first with persistent AGPR bias4 as C-input; the 16
//     per-substep acc-init movs are gone.
//  2. One-rcp c-update: c = (c*dA + K2*(G-1)*e) * rcp(dA*e), dA=(1+A)(G+1),
//     e=1+F. Exact rewrite of f*c+i*g; 8 -> 7 trans per output.
// Predicted: kernel ~99-103us, VALUBusy ~29-31, MfmaUtil ~23.5-24.5.

#define HDIM 128
#define TSTEPS 128
#define NPLAYER 1408
#define NSEQ 1472
#define NB 8
#define NBLK (NSEQ / NB)        // 184
#define NPBLK (NPLAYER / NB)    // 176
#define KT 5                    // k-tiles of 32 (K_aug = 160; kt4 = x aug)
#define BSTR 168                // fp16 per B row (336 B stride, proven layout)
#define HSTR 132                // floats per hbuf row (16B-aligned, pad 4)

typedef _Float16 f16x8 __attribute__((ext_vector_type(8)));
typedef _Float16 f16x2 __attribute__((ext_vector_type(2)));
typedef float    f32x4 __attribute__((ext_vector_type(4)));

#define LOG2E 1.4426950408889634f
#define K2    2.8853900817779268f   // 2*log2(e)

__device__ __forceinline__ float rcp_fast(float x)  { return __builtin_amdgcn_rcpf(x); }
__device__ __forceinline__ float exp2_fast(float x) { return __builtin_amdgcn_exp2f(x); }

__global__ void __launch_bounds__(512)
__attribute__((amdgpu_waves_per_eu(2, 2)))
lstm_fc_kernel(const float* __restrict__ x_players, const float* __restrict__ x_ball,
               const float* __restrict__ p_w_ih, const float* __restrict__ p_w_hh,
               const float* __restrict__ p_b_ih, const float* __restrict__ p_b_hh,
               const float* __restrict__ b_w_ih, const float* __restrict__ b_w_hh,
               const float* __restrict__ b_b_ih, const float* __restrict__ b_b_hh,
               const float* __restrict__ fc_w, const float* __restrict__ fc_b,
               float* __restrict__ out)
{
    const int tid  = threadIdx.x;
    const int blk  = blockIdx.x;          // 0..183; 176..183 ball
    const int w    = tid >> 6;            // wave -> h-rows [16w, 16w+16)
    const int lane = tid & 63;
    const int nn   = lane & 15;           // MFMA n (col)
    const int q    = lane >> 4;           // MFMA quad

    const bool ball = (blk >= NPBLK);
    const float* w_ih = ball ? b_w_ih : p_w_ih;
    const float* w_hh = ball ? b_w_hh : p_w_hh;
    const float* bih  = ball ? b_b_ih : p_b_ih;
    const float* bhh  = ball ? b_b_hh : p_b_hh;
    const float* xg   = ball ? (x_ball    + (size_t)(blk - NPBLK) * NB * TSTEPS * 2)
                             : (x_players + (size_t)blk * NB * TSTEPS * 2);

    __shared__ __align__(16) _Float16 b_sh[2][NB * BSTR];
    __shared__ __align__(4)  f16x2 x_tab[TSTEPS * NB];   // [t][seq], fp16 pairs
    __shared__ __align__(16) float hbuf[NB * HSTR];      // final h, fp32
    __shared__ float vout[NB * 40];                      // ball-path per-batch fc part

    // zero h double-buffers (buf0 = h(-1) = 0; buf1 fully overwritten each step)
    for (int i = tid; i < 2 * NB * BSTR / 2; i += 512)
        ((int*)b_sh)[i] = 0;
    // static fp16 x table (coalesced: t fastest)
    for (int i = tid; i < TSTEPS * NB; i += 512) {
        const int sq = i >> 7, t = i & 127;
        const float2 xv2 = ((const float2*)xg)[sq * TSTEPS + t];
        x_tab[t * NB + sq] = (f16x2){(_Float16)xv2.x, (_Float16)xv2.y};
    }

    // ---- A fragments (pre-scaled): gate mi, row r = mi*128 + 16w + nn.
    // a[j] = A[m=lane&15][k = 32kt + 8q + j]; kt=4 aug: k=128:wi0 129:wi1
    const int rowoff = (nn < 8) ? 0 : 2;        // which acc regs this lane keeps
    f16x8 afr[4][KT];
    f32x4 bias4[4];                             // persistent aug-MFMA C input (AGPR)
    #pragma unroll
    for (int mi = 0; mi < 4; ++mi) {
        const float sc = (mi == 2) ? K2 : LOG2E;   // g gate gets 2*log2e
        const int r = mi * HDIM + w * 16 + nn;
        const float* wr = w_hh + (size_t)r * HDIM;
        #pragma unroll
        for (int kt = 0; kt < 4; ++kt) {
            const float* p = wr + kt * 32 + q * 8;
            f16x8 a8;
            #pragma unroll
            for (int j = 0; j < 8; ++j) a8[j] = (_Float16)(sc * p[j]);
            afr[mi][kt] = a8;
        }
        f16x8 a8 = {};
        if (q == 0) {
            a8[0] = (_Float16)(sc * w_ih[2 * r]);
            a8[1] = (_Float16)(sc * w_ih[2 * r + 1]);
        }
        afr[mi][4] = a8;
        // bias for this lane's kept C/D rows (4q+rowoff, +1), pre-scaled.
        // C reg j = row 4q+j; kept regs are {rowoff, rowoff+1}, so {b0,b1,b0,b1}
        // is correct for both nn<8 (regs 0,1) and nn>=8 (regs 2,3).
        const int rb = mi * HDIM + w * 16 + 4 * q + rowoff;
        const float b0 = sc * (bih[rb] + bhh[rb]);
        const float b1 = sc * (bih[rb + 1] + bhh[rb + 1]);
        bias4[mi] = (f32x4){b0, b1, b0, b1};
    }

    const int colh = nn & 7;                    // owned seq col (dup across nn^8)
    const int hrow = w * 16 + 4 * q + rowoff;   // first of 2 owned h-rows
    float c0 = 0.f, c1 = 0.f;                   // c kept in 2*log2e scale
    float h0 = 0.f, h1 = 0.f;

    __syncthreads();

    f16x8 bx = {};   // aug B frag: words 2..7 stay zero forever

    auto substep = [&](int s, const _Float16* bc, _Float16* bn, bool last) {
        const f16x2 xv = x_tab[s * NB + colh];
        f16x8 bfr[4];
        const _Float16* bp = bc + colh * BSTR + q * 8;
        #pragma unroll
        for (int kt = 0; kt < 4; ++kt)
            bfr[kt] = *(const f16x8*)(bp + kt * 32);
        bx[0] = xv[0]; bx[1] = xv[1];

        // aug MFMA first: C = persistent AGPR bias (no init movs, no class copies)
        f32x4 acc[4];
        #pragma unroll
        for (int mi = 0; mi < 4; ++mi)
            acc[mi] = __builtin_amdgcn_mfma_f32_16x16x32_f16(afr[mi][4], bx, bias4[mi], 0, 0, 0);
        #pragma unroll
        for (int kt = 0; kt < 4; ++kt)
            #pragma unroll
            for (int mi = 0; mi < 4; ++mi)
                acc[mi] = __builtin_amdgcn_mfma_f32_16x16x32_f16(afr[mi][kt], bfr[kt], acc[mi], 0, 0, 0);

        // B cols duplicated -> lane nn>=8's own regs {2,3} are rows 4q+2,4q+3
        float u0[4], u1[4];
        #pragma unroll
        for (int mi = 0; mi < 4; ++mi) {
            u0[mi] = (nn < 8) ? acc[mi][0] : acc[mi][2];
            u1[mi] = (nn < 8) ? acc[mi][1] : acc[mi][3];
        }

        // u pre-scaled: [0]=i',[1]=f',[3]=o' (log2e); [2]=g' (2*log2e)
        const float A0 = exp2_fast(-u0[0]), A1 = exp2_fast(-u1[0]);
        const float F0 = exp2_fast(-u0[1]), F1 = exp2_fast(-u1[1]);
        const float G0 = exp2_fast( u0[2]), G1 = exp2_fast( u1[2]);
        const float O0 = exp2_fast(-u0[3]), O1 = exp2_fast(-u1[3]);
        // c' = f*c' + K2*i*g  ==  (c'*dA + K2*(G-1)*e) * rcp(dA*e),
        // dA = (1+A)(G+1), e = 1+F   (one rcp instead of two; exact rewrite)
        const float dA0 = (1.0f + A0) * (G0 + 1.0f);
        const float dA1 = (1.0f + A1) * (G1 + 1.0f);
        const float t0  = __builtin_fmaf(G0, K2, -K2);
        const float t1  = __builtin_fmaf(G1, K2, -K2);
        const float e0  = 1.0f + F0;
        const float e1  = 1.0f + F1;
        const float rd0 = rcp_fast(dA0 * e0);
        const float rd1 = rcp_fast(dA1 * e1);
        c0 = __builtin_fmaf(c0, dA0, t0 * e0) * rd0;
        c1 = __builtin_fmaf(c1, dA1, t1 * e1) * rd1;
        const float C0 = exp2_fast(c0), C1 = exp2_fast(c1);
        // h = o*tanh(c) = (C-1) * rcp((C+1)(1+O))
        const float rr0 = rcp_fast((C0 + 1.0f) * (1.0f + O0));
        const float rr1 = rcp_fast((C1 + 1.0f) * (1.0f + O1));
        h0 = (C0 - 1.0f) * rr0;
        h1 = (C1 - 1.0f) * rr1;

        if (!last) {
            *(f16x2*)&bn[colh * BSTR + hrow] = (f16x2){(_Float16)h0, (_Float16)h1};
            __syncthreads();
        }
    };

    _Float16* b0 = &b_sh[0][0];
    _Float16* b1 = &b_sh[1][0];
    #pragma unroll 1
    for (int it = 0; it < TSTEPS / 2 - 1; ++it) {   // steps 0..125
        substep(2 * it,     b0, b1, false);
        substep(2 * it + 1, b1, b0, false);
        // loop-carried AGPR pins: block rematerialization (R1..R5 failure mode)
        asm volatile("" : "+a"(afr[0][0]), "+a"(afr[0][1]), "+a"(afr[0][2]), "+a"(afr[0][3]), "+a"(afr[0][4]));
        asm volatile("" : "+a"(afr[1][0]), "+a"(afr[1][1]), "+a"(afr[1][2]), "+a"(afr[1][3]), "+a"(afr[1][4]));
        asm volatile("" : "+a"(afr[2][0]), "+a"(afr[2][1]), "+a"(afr[2][2]), "+a"(afr[2][3]), "+a"(afr[2][4]));
        asm volatile("" : "+a"(afr[3][0]), "+a"(afr[3][1]), "+a"(afr[3][2]), "+a"(afr[3][3]), "+a"(afr[3][4]));
        asm volatile("" : "+a"(bias4[0]), "+a"(bias4[1]), "+a"(bias4[2]), "+a"(bias4[3]));
    }
    substep(126, b0, b1, false);
    substep(127, b1, b0, true);    // peeled: no h-write, no barrier

    // ---- final h -> LDS (fp32), then fused FC epilogue ----
    hbuf[colh * HSTR + hrow]     = h0;
    hbuf[colh * HSTR + hrow + 1] = h1;
    __syncthreads();

    if (!ball) {
        // player part: out[gp*40+row] += fc_b[row] + fc_w[row, 0:128] . h(gp)
        for (int o = tid; o < NB * 40; o += 512) {
            const int j = o / 40, row = o - j * 40;
            const float* wr = fc_w + (size_t)row * 2 * HDIM;        // cols 0..127
            const float* hp = &hbuf[j * HSTR];
            float a0 = fc_b[row], a1 = 0.f, a2 = 0.f, a3 = 0.f;
            #pragma unroll
            for (int k = 0; k < HDIM; k += 4) {
                float4 wv = *(const float4*)(wr + k);
                float4 hv = *(const float4*)(hp + k);
                a0 = __builtin_fmaf(wv.x, hv.x, a0);
                a1 = __builtin_fmaf(wv.y, hv.y, a1);
                a2 = __builtin_fmaf(wv.z, hv.z, a2);
                a3 = __builtin_fmaf(wv.w, hv.w, a3);
            }
            atomicAdd(&out[(size_t)(NB * blk + j) * 40 + row], (a0 + a1) + (a2 + a3));
        }
    } else {
        // ball part: v[c][row] = fc_w[row, 128:256] . ball_h(batch), then
        // broadcast-add to the batch's 22 players.
        for (int o = tid; o < NB * 40; o += 512) {
            const int c = o / 40, row = o - c * 40;
            const float* wr = fc_w + (size_t)row * 2 * HDIM + HDIM;  // cols 128..255
            const float* hp = &hbuf[c * HSTR];
            float a0 = 0.f, a1 = 0.f, a2 = 0.f, a3 = 0.f;
            #pragma unroll
            for (int k = 0; k < HDIM; k += 4) {
                float4 wv = *(const float4*)(wr + k);
                float4 hv = *(const float4*)(hp + k);
                a0 = __builtin_fmaf(wv.x, hv.x, a0);
                a1 = __builtin_fmaf(wv.y, hv.y, a1);
                a2 = __builtin_fmaf(wv.z, hv.z, a2);
                a3 = __builtin_fmaf(wv.w, hv.w, a3);
            }
            vout[c * 40 + row] = (a0 + a1) + (a2 + a3);
        }
        __syncthreads();
        const int base_batch = (blk - NPBLK) * NB;
        for (int o = tid; o < NB * 22 * 40; o += 512) {
            const int c = o / 880, rem = o - c * 880;
            const int p = rem / 40, row = rem - p * 40;
            atomicAdd(&out[(size_t)((base_batch + c) * 22 + p) * 40 + row],
                      vout[c * 40 + row]);
        }
    }
}

extern "C" void kernel_launch(void* const* d_in, const int* in_sizes, int n_in,
                              void* d_out, int out_size, void* d_ws, size_t ws_size,
                              hipStream_t stream) {
    const float* x_players = (const float*)d_in[0];
    const float* x_ball    = (const float*)d_in[1];
    const float* p_w_ih    = (const float*)d_in[2];
    const float* p_w_hh    = (const float*)d_in[3];
    const float* p_b_ih    = (const float*)d_in[4];
    const float* p_b_hh    = (const float*)d_in[5];
    const float* b_w_ih    = (const float*)d_in[6];
    const float* b_w_hh    = (const float*)d_in[7];
    const float* b_b_ih    = (const float*)d_in[8];
    const float* b_b_hh    = (const float*)d_in[9];
    const float* fc_w      = (const float*)d_in[10];
    const float* fc_b      = (const float*)d_in[11];

    // zero the output: both block types accumulate into it atomically
    hipMemsetAsync(d_out, 0, (size_t)out_size * sizeof(float), stream);

    lstm_fc_kernel<<<dim3(NBLK), dim3(512), 0, stream>>>(
        x_players, x_ball, p_w_ih, p_w_hh, p_b_ih, p_b_hh,
        b_w_ih, b_w_hh, b_b_ih, b_b_hh, fc_w, fc_b, (float*)d_out);
}

// Round 6
// 167.135 us; speedup vs baseline: 1.0898x; 1.0433x over previous
//
#include <hip/hip_runtime.h>

// TeamMovementModel R16b: R16 with the cvt_pkrtz type fixed (__fp16 vector
// return type vs _Float16 vector — compile error only; no measurement lost).
// Base: R13's measured-best structure (106.6us, VALUBusy 33.2) + two local,
// allocation-neutral swaps.
// R14/R15 post-mortem: bias-as-C + aug-first regressed twice (+20-30 VALU
// insts/wave/substep, VALUBusy 33->42/40) regardless of bias register class
// -> that restructure makes the allocator emit copy traffic; abandoned.
// Kept (arithmetic-only):
//  1. One-rcp c-update: c = (c*dA + K2*(G-1)*e) * rcp(dA*e), dA=(1+A)(G+1),
//     e=1+F. Exact rewrite of f*c+i*g; 8 -> 7 trans per output (-8 cyc/wave).
//  2. v_cvt_pkrtz_f16_f32 packed h-store: 1 inst vs cvt,cvt,pack (-4 cyc/wave).
// Predicted: kernel ~104-106us, VALUBusy ~31.5-32.5, MfmaUtil ~23.

#define HDIM 128
#define TSTEPS 128
#define NPLAYER 1408
#define NSEQ 1472
#define NB 8
#define NBLK (NSEQ / NB)        // 184
#define NPBLK (NPLAYER / NB)    // 176
#define KT 5                    // k-tiles of 32 (K_aug = 160; kt4 = x aug)
#define BSTR 168                // fp16 per B row (336 B stride, proven layout)
#define HSTR 132                // floats per hbuf row (16B-aligned, pad 4)

typedef _Float16 f16x8 __attribute__((ext_vector_type(8)));
typedef _Float16 f16x2 __attribute__((ext_vector_type(2)));
typedef __fp16   h16x2 __attribute__((ext_vector_type(2)));   // cvt_pkrtz return
typedef float    f32x4 __attribute__((ext_vector_type(4)));

#define LOG2E 1.4426950408889634f
#define K2    2.8853900817779268f   // 2*log2(e)

__device__ __forceinline__ float rcp_fast(float x)  { return __builtin_amdgcn_rcpf(x); }
__device__ __forceinline__ float exp2_fast(float x) { return __builtin_amdgcn_exp2f(x); }

__global__ void __launch_bounds__(512)
__attribute__((amdgpu_waves_per_eu(2, 2)))
lstm_fc_kernel(const float* __restrict__ x_players, const float* __restrict__ x_ball,
               const float* __restrict__ p_w_ih, const float* __restrict__ p_w_hh,
               const float* __restrict__ p_b_ih, const float* __restrict__ p_b_hh,
               const float* __restrict__ b_w_ih, const float* __restrict__ b_w_hh,
               const float* __restrict__ b_b_ih, const float* __restrict__ b_b_hh,
               const float* __restrict__ fc_w, const float* __restrict__ fc_b,
               float* __restrict__ out)
{
    const int tid  = threadIdx.x;
    const int blk  = blockIdx.x;          // 0..183; 176..183 ball
    const int w    = tid >> 6;            // wave -> h-rows [16w, 16w+16)
    const int lane = tid & 63;
    const int nn   = lane & 15;           // MFMA n (col)
    const int q    = lane >> 4;           // MFMA quad

    const bool ball = (blk >= NPBLK);
    const float* w_ih = ball ? b_w_ih : p_w_ih;
    const float* w_hh = ball ? b_w_hh : p_w_hh;
    const float* bih  = ball ? b_b_ih : p_b_ih;
    const float* bhh  = ball ? b_b_hh : p_b_hh;
    const float* xg   = ball ? (x_ball    + (size_t)(blk - NPBLK) * NB * TSTEPS * 2)
                             : (x_players + (size_t)blk * NB * TSTEPS * 2);

    __shared__ __align__(16) _Float16 b_sh[2][NB * BSTR];
    __shared__ __align__(4)  f16x2 x_tab[TSTEPS * NB];   // [t][seq], fp16 pairs
    __shared__ __align__(16) float hbuf[NB * HSTR];      // final h, fp32
    __shared__ float vout[NB * 40];                      // ball-path per-batch fc part

    // zero h double-buffers (buf0 = h(-1) = 0; buf1 fully overwritten each step)
    for (int i = tid; i < 2 * NB * BSTR / 2; i += 512)
        ((int*)b_sh)[i] = 0;
    // static fp16 x table (coalesced: t fastest)
    for (int i = tid; i < TSTEPS * NB; i += 512) {
        const int sq = i >> 7, t = i & 127;
        const float2 xv2 = ((const float2*)xg)[sq * TSTEPS + t];
        x_tab[t * NB + sq] = (f16x2){(_Float16)xv2.x, (_Float16)xv2.y};
    }

    // ---- A fragments (pre-scaled): gate mi, row r = mi*128 + 16w + nn.
    // a[j] = A[m=lane&15][k = 32kt + 8q + j]; kt=4 aug: k=128:wi0 129:wi1
    const int rowoff = (nn < 8) ? 0 : 2;        // which acc regs this lane keeps
    f16x8 afr[4][KT];
    float bias0[4], bias1[4];
    #pragma unroll
    for (int mi = 0; mi < 4; ++mi) {
        const float sc = (mi == 2) ? K2 : LOG2E;   // g gate gets 2*log2e
        const int r = mi * HDIM + w * 16 + nn;
        const float* wr = w_hh + (size_t)r * HDIM;
        #pragma unroll
        for (int kt = 0; kt < 4; ++kt) {
            const float* p = wr + kt * 32 + q * 8;
            f16x8 a8;
            #pragma unroll
            for (int j = 0; j < 8; ++j) a8[j] = (_Float16)(sc * p[j]);
            afr[mi][kt] = a8;
        }
        f16x8 a8 = {};
        if (q == 0) {
            a8[0] = (_Float16)(sc * w_ih[2 * r]);
            a8[1] = (_Float16)(sc * w_ih[2 * r + 1]);
        }
        afr[mi][4] = a8;
        // bias for this lane's C/D rows (4q+rowoff, 4q+rowoff+1), pre-scaled
        const int rb = mi * HDIM + w * 16 + 4 * q + rowoff;
        bias0[mi] = sc * (bih[rb] + bhh[rb]);
        bias1[mi] = sc * (bih[rb + 1] + bhh[rb + 1]);
    }

    const int colh = nn & 7;                    // owned seq col (dup across nn^8)
    const int hrow = w * 16 + 4 * q + rowoff;   // first of 2 owned h-rows
    float c0 = 0.f, c1 = 0.f;                   // c kept in 2*log2e scale
    float h0 = 0.f, h1 = 0.f;

    __syncthreads();

    f16x8 bx = {};   // aug B frag: words 2..7 stay zero forever

    auto substep = [&](int s, const _Float16* bc, _Float16* bn, bool last) {
        f16x8 bfr[4];
        const _Float16* bp = bc + colh * BSTR + q * 8;
        #pragma unroll
        for (int kt = 0; kt < 4; ++kt)
            bfr[kt] = *(const f16x8*)(bp + kt * 32);
        {   // x for this step: broadcast ds_read_b32 (only q==0 A-rows nonzero)
            const f16x2 xv = x_tab[s * NB + colh];
            bx[0] = xv[0]; bx[1] = xv[1];
        }

        f32x4 acc[4];
        #pragma unroll
        for (int mi = 0; mi < 4; ++mi)
            acc[mi] = (f32x4){bias0[mi], bias1[mi], bias0[mi], bias1[mi]};
        #pragma unroll
        for (int kt = 0; kt < 4; ++kt)
            #pragma unroll
            for (int mi = 0; mi < 4; ++mi)
                acc[mi] = __builtin_amdgcn_mfma_f32_16x16x32_f16(afr[mi][kt], bfr[kt], acc[mi], 0, 0, 0);
        #pragma unroll
        for (int mi = 0; mi < 4; ++mi)
            acc[mi] = __builtin_amdgcn_mfma_f32_16x16x32_f16(afr[mi][4], bx, acc[mi], 0, 0, 0);

        // B cols duplicated -> lane nn>=8's own regs {2,3} are rows 4q+2,4q+3
        float u0[4], u1[4];
        #pragma unroll
        for (int mi = 0; mi < 4; ++mi) {
            u0[mi] = (nn < 8) ? acc[mi][0] : acc[mi][2];
            u1[mi] = (nn < 8) ? acc[mi][1] : acc[mi][3];
        }

        // u pre-scaled: [0]=i',[1]=f',[3]=o' (log2e); [2]=g' (2*log2e)
        const float A0 = exp2_fast(-u0[0]), A1 = exp2_fast(-u1[0]);
        const float F0 = exp2_fast(-u0[1]), F1 = exp2_fast(-u1[1]);
        const float G0 = exp2_fast( u0[2]), G1 = exp2_fast( u1[2]);
        const float O0 = exp2_fast(-u0[3]), O1 = exp2_fast(-u1[3]);
        // c' = f*c' + K2*i*g  ==  (c'*dA + K2*(G-1)*e) * rcp(dA*e),
        // dA = (1+A)(G+1), e = 1+F   (one rcp instead of two; exact rewrite)
        const float dA0 = (1.0f + A0) * (G0 + 1.0f);
        const float dA1 = (1.0f + A1) * (G1 + 1.0f);
        const float t0  = __builtin_fmaf(G0, K2, -K2);
        const float t1  = __builtin_fmaf(G1, K2, -K2);
        const float e0  = 1.0f + F0;
        const float e1  = 1.0f + F1;
        const float rd0 = rcp_fast(dA0 * e0);
        const float rd1 = rcp_fast(dA1 * e1);
        c0 = __builtin_fmaf(c0, dA0, t0 * e0) * rd0;
        c1 = __builtin_fmaf(c1, dA1, t1 * e1) * rd1;
        const float C0 = exp2_fast(c0), C1 = exp2_fast(c1);
        // h = o*tanh(c) = (C-1) * rcp((C+1)(1+O))
        const float rr0 = rcp_fast((C0 + 1.0f) * (1.0f + O0));
        const float rr1 = rcp_fast((C1 + 1.0f) * (1.0f + O1));
        h0 = (C0 - 1.0f) * rr0;
        h1 = (C1 - 1.0f) * rr1;

        if (!last) {
            // packed RTZ convert: 1 inst vs cvt+cvt+pack (store via __fp16x2,
            // layout-identical to f16x2; address is 4B-aligned: hrow even)
            *(h16x2*)&bn[colh * BSTR + hrow] = __builtin_amdgcn_cvt_pkrtz(h0, h1);
            __syncthreads();
        }
    };

    _Float16* b0 = &b_sh[0][0];
    _Float16* b1 = &b_sh[1][0];
    #pragma unroll 1
    for (int it = 0; it < TSTEPS / 2 - 1; ++it) {   // steps 0..125
        substep(2 * it,     b0, b1, false);
        substep(2 * it + 1, b1, b0, false);
        // loop-carried AGPR pins: block rematerialization (R1..R5 failure mode)
        asm volatile("" : "+a"(afr[0][0]), "+a"(afr[0][1]), "+a"(afr[0][2]), "+a"(afr[0][3]), "+a"(afr[0][4]));
        asm volatile("" : "+a"(afr[1][0]), "+a"(afr[1][1]), "+a"(afr[1][2]), "+a"(afr[1][3]), "+a"(afr[1][4]));
        asm volatile("" : "+a"(afr[2][0]), "+a"(afr[2][1]), "+a"(afr[2][2]), "+a"(afr[2][3]), "+a"(afr[2][4]));
        asm volatile("" : "+a"(afr[3][0]), "+a"(afr[3][1]), "+a"(afr[3][2]), "+a"(afr[3][3]), "+a"(afr[3][4]));
    }
    substep(126, b0, b1, false);
    substep(127, b1, b0, true);    // peeled: no h-write, no barrier

    // ---- final h -> LDS (fp32), then fused FC epilogue ----
    hbuf[colh * HSTR + hrow]     = h0;
    hbuf[colh * HSTR + hrow + 1] = h1;
    __syncthreads();

    if (!ball) {
        // player part: out[gp*40+row] += fc_b[row] + fc_w[row, 0:128] . h(gp)
        for (int o = tid; o < NB * 40; o += 512) {
            const int j = o / 40, row = o - j * 40;
            const float* wr = fc_w + (size_t)row * 2 * HDIM;        // cols 0..127
            const float* hp = &hbuf[j * HSTR];
            float a0 = fc_b[row], a1 = 0.f, a2 = 0.f, a3 = 0.f;
            #pragma unroll
            for (int k = 0; k < HDIM; k += 4) {
                float4 wv = *(const float4*)(wr + k);
                float4 hv = *(const float4*)(hp + k);
                a0 = __builtin_fmaf(wv.x, hv.x, a0);
                a1 = __builtin_fmaf(wv.y, hv.y, a1);
                a2 = __builtin_fmaf(wv.z, hv.z, a2);
                a3 = __builtin_fmaf(wv.w, hv.w, a3);
            }
            atomicAdd(&out[(size_t)(NB * blk + j) * 40 + row], (a0 + a1) + (a2 + a3));
        }
    } else {
        // ball part: v[c][row] = fc_w[row, 128:256] . ball_h(batch), then
        // broadcast-add to the batch's 22 players.
        for (int o = tid; o < NB * 40; o += 512) {
            const int c = o / 40, row = o - c * 40;
            const float* wr = fc_w + (size_t)row * 2 * HDIM + HDIM;  // cols 128..255
            const float* hp = &hbuf[c * HSTR];
            float a0 = 0.f, a1 = 0.f, a2 = 0.f, a3 = 0.f;
            #pragma unroll
            for (int k = 0; k < HDIM; k += 4) {
                float4 wv = *(const float4*)(wr + k);
                float4 hv = *(const float4*)(hp + k);
                a0 = __builtin_fmaf(wv.x, hv.x, a0);
                a1 = __builtin_fmaf(wv.y, hv.y, a1);
                a2 = __builtin_fmaf(wv.z, hv.z, a2);
                a3 = __builtin_fmaf(wv.w, hv.w, a3);
            }
            vout[c * 40 + row] = (a0 + a1) + (a2 + a3);
        }
        __syncthreads();
        const int base_batch = (blk - NPBLK) * NB;
        for (int o = tid; o < NB * 22 * 40; o += 512) {
            const int c = o / 880, rem = o - c * 880;
            const int p = rem / 40, row = rem - p * 40;
            atomicAdd(&out[(size_t)((base_batch + c) * 22 + p) * 40 + row],
                      vout[c * 40 + row]);
        }
    }
}

extern "C" void kernel_launch(void* const* d_in, const int* in_sizes, int n_in,
                              void* d_out, int out_size, void* d_ws, size_t ws_size,
                              hipStream_t stream) {
    const float* x_players = (const float*)d_in[0];
    const float* x_ball    = (const float*)d_in[1];
    const float* p_w_ih    = (const float*)d_in[2];
    const float* p_w_hh    = (const float*)d_in[3];
    const float* p_b_ih    = (const float*)d_in[4];
    const float* p_b_hh    = (const float*)d_in[5];
    const float* b_w_ih    = (const float*)d_in[6];
    const float* b_w_hh    = (const float*)d_in[7];
    const float* b_b_ih    = (const float*)d_in[8];
    const float* b_b_hh    = (const float*)d_in[9];
    const float* fc_w      = (const float*)d_in[10];
    const float* fc_b      = (const float*)d_in[11];

    // zero the output: both block types accumulate into it atomically
    hipMemsetAsync(d_out, 0, (size_t)out_size * sizeof(float), stream);

    lstm_fc_kernel<<<dim3(NBLK), dim3(512), 0, stream>>>(
        x_players, x_ball, p_w_ih, p_w_hh, p_b_ih, p_b_hh,
        b_w_ih, b_w_hh, b_b_ih, b_b_hh, fc_w, fc_b, (float*)d_out);
}